// Round 1
// baseline (217.123 us; speedup 1.0000x reference)
//
#include <hip/hip_runtime.h>

// HolomorphicHealingBackprop: df is trivially 4.0 everywhere, so
// alpha = tanh(4) is a constant and mask == 1. Per quaternion q = (w,x,y,z):
//   h = normalize_eps( (t*w + a, -t*x, -t*y, -t*z) ),  t = 1 - a
//   out = normalize_eps( q (Hamilton) h )
// Pure streaming kernel: 16 B in / 16 B out per thread -> HBM-bound.

#define ALPHA_T 0.9993292997390670f  // tanh(4.0)

__global__ __launch_bounds__(256) void heal_kernel(
    const float4* __restrict__ xin, float4* __restrict__ out, int n_quat) {
  int i = blockIdx.x * blockDim.x + threadIdx.x;
  if (i >= n_quat) return;

  float4 q = xin[i];

  const float a = ALPHA_T;
  const float t = 1.0f - a;

  // correction * conj_sign
  float h0 = t * q.x + a;
  float h1 = -t * q.y;
  float h2 = -t * q.z;
  float h3 = -t * q.w;

  // normalize with +1e-8 (matches reference EPS)
  float n1 = sqrtf(h0 * h0 + h1 * h1 + h2 * h2 + h3 * h3);
  float inv1 = 1.0f / (n1 + 1e-8f);
  h0 *= inv1; h1 *= inv1; h2 *= inv1; h3 *= inv1;

  // Hamilton product q * h, q = (q.x, q.y, q.z, q.w) as (w,x,y,z)
  float ow = q.x * h0 - q.y * h1 - q.z * h2 - q.w * h3;
  float ox = q.x * h1 + q.y * h0 + q.z * h3 - q.w * h2;
  float oy = q.x * h2 - q.y * h3 + q.z * h0 + q.w * h1;
  float oz = q.x * h3 + q.y * h2 - q.z * h1 + q.w * h0;

  // final normalize with +1e-8
  float n2 = sqrtf(ow * ow + ox * ox + oy * oy + oz * oz);
  float inv2 = 1.0f / (n2 + 1e-8f);

  out[i] = make_float4(ow * inv2, ox * inv2, oy * inv2, oz * inv2);
}

extern "C" void kernel_launch(void* const* d_in, const int* in_sizes, int n_in,
                              void* d_out, int out_size, void* d_ws, size_t ws_size,
                              hipStream_t stream) {
  const float4* x = (const float4*)d_in[0];
  float4* out = (float4*)d_out;
  int n_quat = in_sizes[0] / 4;  // 8,388,608 quaternions

  int block = 256;
  int grid = (n_quat + block - 1) / block;
  heal_kernel<<<grid, block, 0, stream>>>(x, out, n_quat);
}